// Round 17
// baseline (69.435 us; speedup 1.0000x reference)
//
#include <hip/hip_runtime.h>

typedef __attribute__((ext_vector_type(8))) short bf16x8;
typedef __attribute__((ext_vector_type(4))) float f32x4;
typedef __attribute__((ext_vector_type(16))) float f32x16;

#define DI __device__ __forceinline__

DI unsigned short f2bf(float f) {
    unsigned int u = __builtin_bit_cast(unsigned int, f);
    u += 0x7fff + ((u >> 16) & 1);
    return (unsigned short)(u >> 16);
}

DI unsigned int cvtpk(float lo, float hi) {
    unsigned int r;
    asm("v_cvt_pk_bf16_f32 %0, %1, %2" : "=v"(r) : "v"(lo), "v"(hi));
    return r;
}

DI float fexp2(float x) {
    float r;
    asm("v_exp_f32 %0, %1" : "=v"(r) : "v"(x));
    return r;
}

DI void gl_lds16(const void* g, void* l) {
    __builtin_amdgcn_global_load_lds(
        (const __attribute__((address_space(1))) unsigned int*)g,
        (__attribute__((address_space(3))) unsigned int*)l, 16, 0, 0);
}

#define WAITCNT(n) asm volatile("s_waitcnt vmcnt(" #n ")" ::: "memory")

// ---------------------------------------------------------------------------
// Kernel 0: Wt[m][c][k] = W_m[k][c] * scale_m (bf16). m: 0=q(scaled),1=k,2=v
// scale_q = 0.125 * log2(e) -> softmax in exp2 domain downstream. (R13)
// ---------------------------------------------------------------------------
__global__ __launch_bounds__(256) void wt_kernel(
    const float* __restrict__ Wk, const float* __restrict__ Wq,
    const float* __restrict__ Wv, unsigned short* __restrict__ Wt)
{
    __shared__ float ws[64][65];
    const int m = blockIdx.x >> 4, kc = blockIdx.x & 15;
    const float* W = (m == 0) ? Wq : (m == 1) ? Wk : Wv;
    const float scale = (m == 0) ? 0.18033688011112042f : 1.0f;
    const int tid = threadIdx.x;
    #pragma unroll
    for (int r = 0; r < 16; ++r) {
        int idx = r * 256 + tid;
        ws[idx >> 6][idx & 63] = W[(kc * 64 + (idx >> 6)) * 64 + (idx & 63)] * scale;
    }
    __syncthreads();
    const int c = tid >> 2, k4 = (tid & 3) * 16;
    bf16x8 o0, o1;
    #pragma unroll
    for (int j = 0; j < 8; ++j) o0[j] = (short)f2bf(ws[k4 + j][c]);
    #pragma unroll
    for (int j = 0; j < 8; ++j) o1[j] = (short)f2bf(ws[k4 + 8 + j][c]);
    unsigned short* dst = Wt + ((size_t)m * 64 + c) * 1024 + kc * 64 + k4;
    *(bf16x8*)dst = o0;
    *(bf16x8*)(dst + 8) = o1;
}

// ---------------------------------------------------------------------------
// Kernel 1: proj (R13 verbatim). 3-buffer LDS, depth-2 prefetch, counted vmcnt.
// ---------------------------------------------------------------------------
__global__ __launch_bounds__(256) void proj_kernel(
    const float* __restrict__ x, const unsigned short* __restrict__ Wt,
    unsigned short* __restrict__ qw, unsigned short* __restrict__ kw,
    unsigned short* __restrict__ vT)
{
    __shared__ char LDSx[3][8192];
    __shared__ char LDSb[3][6144];

    const int tid = threadIdx.x;
    const int w = tid >> 6, l = tid & 63;
    const int xr = l & 15, lg = l >> 4;
    const int rb = blockIdx.x & 255, ch = blockIdx.x >> 8;
    const int row0 = rb * 64;

    const char* xsrc = (const char*)x + (size_t)row0 * 4096;
    const char* Wtb = (const char*)Wt;

    const int xrow_l = l >> 3, xcb = (l & 7) * 16;
    const int brow_l = l >> 2, bcb = (l & 3) * 16;

    auto stage = [&](int nb, int s) {
        #pragma unroll
        for (int c = 0; c < 4; ++c) {
            const int ci = w + 4 * c;
            if (ci < 8) {
                const int row = ci * 8 + xrow_l;
                const int sw = (row & 7) << 4;
                gl_lds16(xsrc + (size_t)row * 4096 + (size_t)s * 128 + (xcb ^ sw),
                         LDSx[nb] + ci * 1024);
            } else if (ci < 14) {
                const int c8 = ci - 8;
                const int r = c8 * 16 + brow_l;
                const int sw = ((r >> 1) & 3) << 4;
                const int wtrow = (r >> 5) * 64 + ch * 32 + (r & 31);
                gl_lds16(Wtb + (size_t)wtrow * 2048 + (size_t)s * 64 + (bcb ^ sw),
                         LDSb[nb] + c8 * 1024);
            }
        }
    };

    f32x4 acc[3][2];
    #pragma unroll
    for (int m = 0; m < 3; ++m)
        #pragma unroll
        for (int tt = 0; tt < 2; ++tt) { f32x4 z = {0.f,0.f,0.f,0.f}; acc[m][tt] = z; }

    const int Rw = w * 16 + xr;
    const int swx = (Rw & 7) << 4;

    auto compute = [&](int pb) {
        float4 va = *(const float4*)(LDSx[pb] + Rw * 128 + ((32 * lg) ^ swx));
        float4 vb = *(const float4*)(LDSx[pb] + Rw * 128 + ((32 * lg + 16) ^ swx));
        uint4 au;
        au.x = cvtpk(va.x, va.y); au.y = cvtpk(va.z, va.w);
        au.z = cvtpk(vb.x, vb.y); au.w = cvtpk(vb.z, vb.w);
        bf16x8 a = __builtin_bit_cast(bf16x8, au);
        __builtin_amdgcn_s_setprio(1);
        #pragma unroll
        for (int m = 0; m < 3; ++m)
            #pragma unroll
            for (int tt = 0; tt < 2; ++tt) {
                const int rB = m * 32 + tt * 16 + xr;
                bf16x8 bfr = *(const bf16x8*)(LDSb[pb] + rB * 64 +
                                ((16 * lg) ^ (((rB >> 1) & 3) << 4)));
                acc[m][tt] = __builtin_amdgcn_mfma_f32_16x16x32_bf16(a, bfr, acc[m][tt], 0, 0, 0);
            }
        __builtin_amdgcn_s_setprio(0);
    };

    stage(0, 0); stage(1, 1);

    int cb = 0, nb = 2;
    for (int s = 0; s < 32; ++s) {
        if (s == 31) { WAITCNT(0); }
        else if (w < 2) { WAITCNT(4); }
        else { WAITCNT(3); }
        __builtin_amdgcn_sched_barrier(0);
        __builtin_amdgcn_s_barrier();
        if (s + 2 < 32) stage(nb, s + 2);
        compute(cb);
        cb = (cb == 2) ? 0 : cb + 1;
        nb = (nb == 2) ? 0 : nb + 1;
    }

    const int bb = row0 >> 12;
    #pragma unroll
    for (int tt = 0; tt < 2; ++tt) {
        const int col = ch * 32 + tt * 16 + xr;
        #pragma unroll
        for (int i = 0; i < 4; ++i) {
            const int grow = row0 + w * 16 + 4 * lg + i;
            qw[(size_t)grow * 64 + col] = f2bf(acc[0][tt][i]);
            kw[(size_t)grow * 64 + col] = f2bf(acc[1][tt][i]);
        }
        uint2 pv;
        pv.x = cvtpk(acc[2][tt][0], acc[2][tt][1]);
        pv.y = cvtpk(acc[2][tt][2], acc[2][tt][3]);
        const int lr0 = (row0 & 4095) + w * 16 + 4 * lg;
        *(uint2*)&vT[((size_t)bb * 64 + col) * 4096 + lr0] = pv;
    }
}

// ---------------------------------------------------------------------------
// Kernel 2: flash attention, 32x32x16 MFMA, wave = 32 q-rows, WG = 128 rows.
// P in registers (cvt_pk + permlane32_swap, verified R16). Fixed M=0, raw
// v_exp, 2-deep pipeline, counted vmcnt, heavy-first dispatch.
// CHUNK = 256 keys (4 tiles) -> 1088 active WGs (vs R16's 576).
// id: qb = 31-(id&31), b=(id>>5)&3, c=id>>7 in [0,16).
// ---------------------------------------------------------------------------
__global__ __launch_bounds__(256) void attn_kernel(
    const unsigned short* __restrict__ qw, const unsigned short* __restrict__ kw,
    const unsigned short* __restrict__ vT,
    unsigned short* __restrict__ POb, float* __restrict__ Pl)
{
    __shared__ __align__(16) unsigned short Kb[2][4096];   // [key][d], swizzled
    __shared__ __align__(16) unsigned short Vb[2][4096];   // [d][key], swizzled

    const int id = blockIdx.x;
    const int qb = 31 - (id & 31);          // heavy-first
    const int b  = (id >> 5) & 3;
    const int c  = id >> 7;                 // 0..15, 4 tiles each
    const int ntt = 2 * qb + 2;
    const int t0 = c * 4;
    if (t0 >= ntt) return;

    const int tid = threadIdx.x;
    const int w = tid >> 6, l = tid & 63;
    const int q32 = l & 31, h = l >> 5;

    const int rem0 = ntt - t0;
    const int tcnt = rem0 < 4 ? rem0 : 4;
    const size_t base = (size_t)b * 4096;
    const int qrow0 = qb * 128 + w * 32;    // wave's first local q-row
    const int myrow = qrow0 + q32;          // this lane's q-row (B-frag col)

    // Q B-fragments: aq[c16], k = 16*c16 + 8h + j
    bf16x8 aq[4];
    #pragma unroll
    for (int c16 = 0; c16 < 4; ++c16)
        aq[c16] = *(const bf16x8*)(qw + (base + myrow) * 64 + 16 * c16 + 8 * h);

    // staging: linear LDS dest, inverse-swizzled global source (R13/R16)
    const int wo0 = w * 2048, wo1 = wo0 + 1024;
    const int o0 = wo0 + 16 * l, o1 = wo1 + 16 * l;
    const int k0sw = (o0 & ~127) | ((o0 & 127) ^ (((o0 >> 7) & 7) << 4));
    const int k1sw = (o1 & ~127) | ((o1 & 127) ^ (((o1 >> 7) & 7) << 4));
    const size_t v0sw = (size_t)(o0 >> 7) * 8192 + ((o0 & 127) ^ (((o0 >> 7) & 7) << 4));
    const size_t v1sw = (size_t)(o1 >> 7) * 8192 + ((o1 & 127) ^ (((o1 >> 7) & 7) << 4));
    const char* kwb  = (const char*)kw + base * 128;
    const char* vtb0 = (const char*)vT + (size_t)b * 64 * 8192;

    auto stage = [&](int bi, int it) {   // exactly 4 loads per wave
        const char* kt = kwb + (size_t)it * 8192;
        gl_lds16(kt + k0sw, (char*)Kb[bi] + wo0);
        gl_lds16(kt + k1sw, (char*)Kb[bi] + wo1);
        const char* vt = vtb0 + (size_t)it * 128;
        gl_lds16(vt + v0sw, (char*)Vb[bi] + wo0);
        gl_lds16(vt + v1sw, (char*)Vb[bi] + wo1);
    };

    f32x16 accO[2];
    #pragma unroll
    for (int dt = 0; dt < 2; ++dt)
        #pragma unroll
        for (int r = 0; r < 16; ++r) accO[dt][r] = 0.f;
    float lsum = 0.f;

    stage(0, t0);
    if (tcnt > 1) stage(1, t0 + 1);

    for (int tt = 0; tt < tcnt; ++tt) {
        const int it = t0 + tt;
        const int bi = tt & 1;
        if (tt + 1 < tcnt) { WAITCNT(4); } else { WAITCNT(0); }
        __builtin_amdgcn_sched_barrier(0);
        __builtin_amdgcn_s_barrier();

        // S^T = K Q^T : two 32-key tiles, K-dim = d in 4 chunks of 16
        const char* kbase = (const char*)Kb[bi];
        f32x16 s2[2];
        #pragma unroll
        for (int kt = 0; kt < 2; ++kt)
            #pragma unroll
            for (int r = 0; r < 16; ++r) s2[kt][r] = 0.f;
        __builtin_amdgcn_s_setprio(1);
        #pragma unroll
        for (int kt = 0; kt < 2; ++kt) {
            const int row = 32 * kt + q32;
            const int sw = (row & 7) << 4;
            #pragma unroll
            for (int c16 = 0; c16 < 4; ++c16) {
                bf16x8 ak = *(const bf16x8*)(kbase + row * 128 + ((32 * c16 + 16 * h) ^ sw));
                s2[kt] = __builtin_amdgcn_mfma_f32_32x32x16_bf16(ak, aq[c16], s2[kt], 0, 0, 0);
            }
        }
        __builtin_amdgcn_s_setprio(0);

        if (it >= 2 * qb) {   // diagonal region (last two tiles of the block)
            #pragma unroll
            for (int kt = 0; kt < 2; ++kt)
                #pragma unroll
                for (int r = 0; r < 16; ++r) {
                    const int key = it * 64 + 32 * kt + (r & 3) + 8 * (r >> 2) + 4 * h;
                    if (key > myrow) s2[kt][r] = -1e30f;
                }
        }

        // P = 2^s (fixed M=0), per-lane lsum partial
        #pragma unroll
        for (int kt = 0; kt < 2; ++kt)
            #pragma unroll
            for (int r = 0; r < 16; ++r) {
                float v = fexp2(s2[kt][r]);
                s2[kt][r] = v;
                lsum += v;
            }

        // pack P -> PV B-fragments entirely in registers (verified R16)
        bf16x8 pa[4];
        #pragma unroll
        for (int kt = 0; kt < 2; ++kt) {
            unsigned ua[8];
            #pragma unroll
            for (int q2 = 0; q2 < 4; ++q2) {
                ua[2 * q2]     = cvtpk(s2[kt][4 * q2],     s2[kt][4 * q2 + 1]);
                ua[2 * q2 + 1] = cvtpk(s2[kt][4 * q2 + 2], s2[kt][4 * q2 + 3]);
            }
            #pragma unroll
            for (int e = 0; e < 2; ++e) {
                unsigned x0 = ua[4 * e + 0], x1 = ua[4 * e + 1];
                unsigned y0 = ua[4 * e + 2], y1 = ua[4 * e + 3];
                asm("v_permlane32_swap_b32 %0, %1" : "+v"(x0), "+v"(y0));
                asm("v_permlane32_swap_b32 %0, %1" : "+v"(x1), "+v"(y1));
                uint4 pu;
                pu.x = x0; pu.y = x1; pu.z = y0; pu.w = y1;
                pa[2 * kt + e] = __builtin_bit_cast(bf16x8, pu);
            }
        }

        // O^T += V^T P^T : two 32-d tiles, K-dim = 64 keys in 4 chunks of 16
        const char* vbase = (const char*)Vb[bi];
        __builtin_amdgcn_s_setprio(1);
        #pragma unroll
        for (int dt = 0; dt < 2; ++dt) {
            const int row = 32 * dt + q32;
            const int sw = (row & 7) << 4;
            #pragma unroll
            for (int kc = 0; kc < 4; ++kc) {
                bf16x8 av = *(const bf16x8*)(vbase + row * 128 + ((32 * kc + 16 * h) ^ sw));
                accO[dt] = __builtin_amdgcn_mfma_f32_32x32x16_bf16(av, pa[kc], accO[dt], 0, 0, 0);
            }
        }
        __builtin_amdgcn_s_setprio(0);

        __builtin_amdgcn_s_barrier();            // all waves done with buf bi
        if (tt + 2 < tcnt) stage(bi, it + 2);    // safe overwrite after barrier
    }

    // epilogue: reduce lsum across halves, store partials
    lsum += __shfl_xor(lsum, 32, 64);

    const size_t prow = (size_t)(b * 16 + c) * 4096 + qrow0;
    #pragma unroll
    for (int dt = 0; dt < 2; ++dt)
        #pragma unroll
        for (int q2 = 0; q2 < 4; ++q2) {
            uint2 uu;
            uu.x = cvtpk(accO[dt][4 * q2],     accO[dt][4 * q2 + 1]);
            uu.y = cvtpk(accO[dt][4 * q2 + 2], accO[dt][4 * q2 + 3]);
            const int d = 32 * dt + 8 * q2 + 4 * h;
            *(uint2*)&POb[(prow + q32) * 64 + d] = uu;
        }
    if (l < 32) Pl[prow + l] = lsum;
}

// ---------------------------------------------------------------------------
// Kernel 3: merge <=16 chunk partials per row -> out. 8 threads/row.
// nc for row lr: qb_row = lr>>7 (128-row blocks); nt = 2*qb_row+2 tiles;
// nc = ceil(nt/4).
// ---------------------------------------------------------------------------
__global__ __launch_bounds__(256) void merge_kernel(
    const unsigned short* __restrict__ POb, const float* __restrict__ Pl,
    float* __restrict__ out)
{
    const int gid = blockIdx.x * 256 + threadIdx.x;   // 0..131071
    const int r = gid >> 3;
    const int c0 = (gid & 7) * 8;
    const int b = r >> 12, lr = r & 4095;
    const int nc = (2 * (lr >> 7) + 5) >> 2;          // ceil((2qb+2)/4)

    float L = 0.f;
    for (int ci = 0; ci < nc; ++ci)
        L += Pl[(size_t)(b * 16 + ci) * 4096 + lr];
    const float rL = 1.0f / L;

    float acc[8];
    #pragma unroll
    for (int j = 0; j < 8; ++j) acc[j] = 0.f;

    for (int ci = 0; ci < nc; ++ci) {
        const unsigned short* p = POb + ((size_t)(b * 16 + ci) * 4096 + lr) * 64 + c0;
        uint4 u = *(const uint4*)p;
        const unsigned int us[4] = {u.x, u.y, u.z, u.w};
        #pragma unroll
        for (int k = 0; k < 4; ++k) {
            acc[2 * k]     += __builtin_bit_cast(float, us[k] << 16);
            acc[2 * k + 1] += __builtin_bit_cast(float, us[k] & 0xFFFF0000u);
        }
    }
    float* op = out + (size_t)r * 64 + c0;
    float4 v0, v1;
    v0.x = acc[0] * rL; v0.y = acc[1] * rL; v0.z = acc[2] * rL; v0.w = acc[3] * rL;
    v1.x = acc[4] * rL; v1.y = acc[5] * rL; v1.z = acc[6] * rL; v1.w = acc[7] * rL;
    *(float4*)op = v0;
    *(float4*)(op + 4) = v1;
}

extern "C" void kernel_launch(void* const* d_in, const int* in_sizes, int n_in,
                              void* d_out, int out_size, void* d_ws, size_t ws_size,
                              hipStream_t stream) {
    const float* x  = (const float*)d_in[0];
    const float* Wk = (const float*)d_in[1];
    const float* Wq = (const float*)d_in[2];
    const float* Wv = (const float*)d_in[3];
    float* out = (float*)d_out;

    char* wsb = (char*)d_ws;
    unsigned short* POb = (unsigned short*)wsb;            // [64][4096][64] bf16 = 32MB
    float* Pl = (float*)(wsb + (size_t)33 * 1024 * 1024);  // [64][4096] f32 = 1MB
    unsigned short* Wt = (unsigned short*)(wsb + (size_t)36 * 1024 * 1024);
    unsigned short* qw = Wt + (size_t)3 * 64 * 1024;       // [16384][64]
    unsigned short* kw = qw + (size_t)16384 * 64;          // [16384][64]
    unsigned short* vT = kw + (size_t)16384 * 64;          // [4][64][4096]

    hipLaunchKernelGGL(wt_kernel, dim3(48), dim3(256), 0, stream, Wk, Wq, Wv, Wt);
    hipLaunchKernelGGL(proj_kernel, dim3(512), dim3(256), 0, stream, x, Wt, qw, kw, vT);
    hipLaunchKernelGGL(attn_kernel, dim3(2048), dim3(256), 0, stream, qw, kw, vT, POb, Pl);
    hipLaunchKernelGGL(merge_kernel, dim3(512), dim3(256), 0, stream, POb, Pl, out);
}

// Round 18
// 59.172 us; speedup vs baseline: 1.1734x; 1.1734x over previous
//
#include <hip/hip_runtime.h>

typedef __attribute__((ext_vector_type(8))) short bf16x8;
typedef __attribute__((ext_vector_type(4))) float f32x4;

#define DI __device__ __forceinline__

DI unsigned short f2bf(float f) {
    unsigned int u = __builtin_bit_cast(unsigned int, f);
    u += 0x7fff + ((u >> 16) & 1);
    return (unsigned short)(u >> 16);
}

DI unsigned int cvtpk(float lo, float hi) {
    unsigned int r;
    asm("v_cvt_pk_bf16_f32 %0, %1, %2" : "=v"(r) : "v"(lo), "v"(hi));
    return r;
}

DI float fexp2(float x) {
    float r;
    asm("v_exp_f32 %0, %1" : "=v"(r) : "v"(x));
    return r;
}

DI void gl_lds16(const void* g, void* l) {
    __builtin_amdgcn_global_load_lds(
        (const __attribute__((address_space(1))) unsigned int*)g,
        (__attribute__((address_space(3))) unsigned int*)l, 16, 0, 0);
}

#define WAITCNT(n) asm volatile("s_waitcnt vmcnt(" #n ")" ::: "memory")

// ---------------------------------------------------------------------------
// Kernel 0: Wt[m][c][k] = W_m[k][c] * scale_m (bf16). m: 0=q(scaled),1=k,2=v
// scale_q = 0.125 * log2(e) -> softmax in exp2 domain downstream.
// ---------------------------------------------------------------------------
__global__ __launch_bounds__(256) void wt_kernel(
    const float* __restrict__ Wk, const float* __restrict__ Wq,
    const float* __restrict__ Wv, unsigned short* __restrict__ Wt)
{
    __shared__ float ws[64][65];
    const int m = blockIdx.x >> 4, kc = blockIdx.x & 15;
    const float* W = (m == 0) ? Wq : (m == 1) ? Wk : Wv;
    const float scale = (m == 0) ? 0.18033688011112042f : 1.0f;
    const int tid = threadIdx.x;
    #pragma unroll
    for (int r = 0; r < 16; ++r) {
        int idx = r * 256 + tid;
        ws[idx >> 6][idx & 63] = W[(kc * 64 + (idx >> 6)) * 64 + (idx & 63)] * scale;
    }
    __syncthreads();
    const int c = tid >> 2, k4 = (tid & 3) * 16;
    bf16x8 o0, o1;
    #pragma unroll
    for (int j = 0; j < 8; ++j) o0[j] = (short)f2bf(ws[k4 + j][c]);
    #pragma unroll
    for (int j = 0; j < 8; ++j) o1[j] = (short)f2bf(ws[k4 + 8 + j][c]);
    unsigned short* dst = Wt + ((size_t)m * 64 + c) * 1024 + kc * 64 + k4;
    *(bf16x8*)dst = o0;
    *(bf16x8*)(dst + 8) = o1;
}

// ---------------------------------------------------------------------------
// Kernel 1: proj. 3-buffer LDS, depth-2 prefetch, counted vmcnt, 1 barrier/step.
// Block = 64 rows x 32-col half; grid 512. A-pack via v_cvt_pk_bf16_f32.
// ---------------------------------------------------------------------------
__global__ __launch_bounds__(256) void proj_kernel(
    const float* __restrict__ x, const unsigned short* __restrict__ Wt,
    unsigned short* __restrict__ qw, unsigned short* __restrict__ kw,
    unsigned short* __restrict__ vT)
{
    __shared__ char LDSx[3][8192];
    __shared__ char LDSb[3][6144];

    const int tid = threadIdx.x;
    const int w = tid >> 6, l = tid & 63;
    const int xr = l & 15, lg = l >> 4;
    const int rb = blockIdx.x & 255, ch = blockIdx.x >> 8;
    const int row0 = rb * 64;

    const char* xsrc = (const char*)x + (size_t)row0 * 4096;
    const char* Wtb = (const char*)Wt;

    const int xrow_l = l >> 3, xcb = (l & 7) * 16;
    const int brow_l = l >> 2, bcb = (l & 3) * 16;

    auto stage = [&](int nb, int s) {
        #pragma unroll
        for (int c = 0; c < 4; ++c) {
            const int ci = w + 4 * c;
            if (ci < 8) {
                const int row = ci * 8 + xrow_l;
                const int sw = (row & 7) << 4;
                gl_lds16(xsrc + (size_t)row * 4096 + (size_t)s * 128 + (xcb ^ sw),
                         LDSx[nb] + ci * 1024);
            } else if (ci < 14) {
                const int c8 = ci - 8;
                const int r = c8 * 16 + brow_l;
                const int sw = ((r >> 1) & 3) << 4;
                const int wtrow = (r >> 5) * 64 + ch * 32 + (r & 31);
                gl_lds16(Wtb + (size_t)wtrow * 2048 + (size_t)s * 64 + (bcb ^ sw),
                         LDSb[nb] + c8 * 1024);
            }
        }
    };

    f32x4 acc[3][2];
    #pragma unroll
    for (int m = 0; m < 3; ++m)
        #pragma unroll
        for (int tt = 0; tt < 2; ++tt) { f32x4 z = {0.f,0.f,0.f,0.f}; acc[m][tt] = z; }

    const int Rw = w * 16 + xr;
    const int swx = (Rw & 7) << 4;

    auto compute = [&](int pb) {
        float4 va = *(const float4*)(LDSx[pb] + Rw * 128 + ((32 * lg) ^ swx));
        float4 vb = *(const float4*)(LDSx[pb] + Rw * 128 + ((32 * lg + 16) ^ swx));
        uint4 au;
        au.x = cvtpk(va.x, va.y); au.y = cvtpk(va.z, va.w);
        au.z = cvtpk(vb.x, vb.y); au.w = cvtpk(vb.z, vb.w);
        bf16x8 a = __builtin_bit_cast(bf16x8, au);
        __builtin_amdgcn_s_setprio(1);
        #pragma unroll
        for (int m = 0; m < 3; ++m)
            #pragma unroll
            for (int tt = 0; tt < 2; ++tt) {
                const int rB = m * 32 + tt * 16 + xr;
                bf16x8 bfr = *(const bf16x8*)(LDSb[pb] + rB * 64 +
                                ((16 * lg) ^ (((rB >> 1) & 3) << 4)));
                acc[m][tt] = __builtin_amdgcn_mfma_f32_16x16x32_bf16(a, bfr, acc[m][tt], 0, 0, 0);
            }
        __builtin_amdgcn_s_setprio(0);
    };

    stage(0, 0); stage(1, 1);

    int cb = 0, nb = 2;
    for (int s = 0; s < 32; ++s) {
        if (s == 31) { WAITCNT(0); }
        else if (w < 2) { WAITCNT(4); }
        else { WAITCNT(3); }
        __builtin_amdgcn_sched_barrier(0);
        __builtin_amdgcn_s_barrier();
        if (s + 2 < 32) stage(nb, s + 2);
        compute(cb);
        cb = (cb == 2) ? 0 : cb + 1;
        nb = (nb == 2) ? 0 : nb + 1;
    }

    const int bb = row0 >> 12;
    #pragma unroll
    for (int tt = 0; tt < 2; ++tt) {
        const int col = ch * 32 + tt * 16 + xr;
        #pragma unroll
        for (int i = 0; i < 4; ++i) {
            const int grow = row0 + w * 16 + 4 * lg + i;
            qw[(size_t)grow * 64 + col] = f2bf(acc[0][tt][i]);
            kw[(size_t)grow * 64 + col] = f2bf(acc[1][tt][i]);
        }
        uint2 pv;
        pv.x = cvtpk(acc[2][tt][0], acc[2][tt][1]);
        pv.y = cvtpk(acc[2][tt][2], acc[2][tt][3]);
        const int lr0 = (row0 & 4095) + w * 16 + 4 * lg;
        *(uint2*)&vT[((size_t)bb * 64 + col) * 4096 + lr0] = pv;
    }
}

// ---------------------------------------------------------------------------
// Kernel 2: flash attention. Fixed M=0, 4 waves x 16 rows, 2-deep pipeline,
// counted vmcnt, raw v_exp, heavy-first XCD-balanced dispatch.
// ---------------------------------------------------------------------------
__global__ __launch_bounds__(256) void attn_kernel(
    const unsigned short* __restrict__ qw, const unsigned short* __restrict__ kw,
    const unsigned short* __restrict__ vT,
    unsigned short* __restrict__ POb, float* __restrict__ Pl)
{
    __shared__ __align__(16) unsigned short Kb[2][4096];   // [key][d], swizzled
    __shared__ __align__(16) unsigned short Vb[2][4096];   // [d][key], swizzled
    __shared__ __align__(16) unsigned short Ps[4][16][64]; // [qrow][key], swizzled

    const int id = blockIdx.x;
    const int qb = 63 - (id & 63);          // heavy-first, balanced across XCDs
    const int b  = (id >> 6) & 3;
    const int c  = id >> 8;
    if (c * 8 > qb) return;

    const int tid = threadIdx.x;
    const int w = tid >> 6, l = tid & 63;
    const int xr = l & 15, g = l >> 4;

    const int t0 = c * 8;
    const int rem0 = qb + 1 - t0;
    const int tcnt = rem0 < 8 ? rem0 : 8;
    const size_t base = (size_t)b * 4096;
    const int qrow = qb * 64 + w * 16;
    const int myrow = qrow + xr;

    bf16x8 aq[2];
    #pragma unroll
    for (int h = 0; h < 2; ++h)
        aq[h] = *(const bf16x8*)(qw + (base + myrow) * 64 + 32 * h + 8 * g);

    const int wo0 = w * 2048, wo1 = wo0 + 1024;
    const int o0 = wo0 + 16 * l, o1 = wo1 + 16 * l;
    const int k0sw = (o0 & ~127) | ((o0 & 127) ^ (((o0 >> 7) & 7) << 4));
    const int k1sw = (o1 & ~127) | ((o1 & 127) ^ (((o1 >> 7) & 7) << 4));
    const size_t v0sw = (size_t)(o0 >> 7) * 8192 + ((o0 & 127) ^ (((o0 >> 7) & 7) << 4));
    const size_t v1sw = (size_t)(o1 >> 7) * 8192 + ((o1 & 127) ^ (((o1 >> 7) & 7) << 4));
    const char* kwb  = (const char*)kw + base * 128;
    const char* vtb0 = (const char*)vT + (size_t)b * 64 * 8192;

    auto stage = [&](int bi, int it) {   // exactly 4 loads per wave
        const char* kt = kwb + (size_t)it * 8192;
        gl_lds16(kt + k0sw, (char*)Kb[bi] + wo0);
        gl_lds16(kt + k1sw, (char*)Kb[bi] + wo1);
        const char* vt = vtb0 + (size_t)it * 128;
        gl_lds16(vt + v0sw, (char*)Vb[bi] + wo0);
        gl_lds16(vt + v1sw, (char*)Vb[bi] + wo1);
    };

    f32x4 accO[4];
    #pragma unroll
    for (int t = 0; t < 4; ++t) { f32x4 z = {0.f,0.f,0.f,0.f}; accO[t] = z; }
    float lsum = 0.f;   // per-lane partial, reduced once in epilogue

    const int swz = (xr & 7) << 4;
    char* const psrow = (char*)Ps + w * 2048 + xr * 128;

    stage(0, t0);
    if (tcnt > 1) stage(1, t0 + 1);

    for (int tt = 0; tt < tcnt; ++tt) {
        const int it = t0 + tt;
        const int bi = tt & 1;
        if (tt + 1 < tcnt) { WAITCNT(4); } else { WAITCNT(0); }
        __builtin_amdgcn_sched_barrier(0);
        __builtin_amdgcn_s_barrier();

        // S^T = K Q^T : lane holds q-row = xr, keys 16t+4g+i
        const char* kbase = (const char*)Kb[bi];
        f32x4 s[4];
        __builtin_amdgcn_s_setprio(1);
        #pragma unroll
        for (int t = 0; t < 4; ++t) {
            f32x4 z = {0.f,0.f,0.f,0.f};
            s[t] = z;
            #pragma unroll
            for (int h = 0; h < 2; ++h) {
                bf16x8 ak = *(const bf16x8*)(kbase + (xr + 16 * t) * 128 + ((64 * h + 16 * g) ^ swz));
                s[t] = __builtin_amdgcn_mfma_f32_16x16x32_bf16(ak, aq[h], s[t], 0, 0, 0);
            }
        }
        __builtin_amdgcn_s_setprio(0);

        if (it == qb) {   // diagonal tile: causal mask
            #pragma unroll
            for (int t = 0; t < 4; ++t)
                #pragma unroll
                for (int i = 0; i < 4; ++i) {
                    const int key = it * 64 + 16 * t + 4 * g + i;
                    if (key > myrow) s[t][i] = -1e30f;
                }
        }

        // P = 2^s with fixed M=0 (no max tracking, no cross-lane ops)
        #pragma unroll
        for (int t = 0; t < 4; ++t)
            #pragma unroll
            for (int i = 0; i < 4; ++i) {
                float v = s[t][i];
                s[t][i] = fexp2(v);
            }

        {
            float a0 = (s[0][0] + s[0][1]) + (s[0][2] + s[0][3]);
            float a1 = (s[1][0] + s[1][1]) + (s[1][2] + s[1][3]);
            float a2 = (s[2][0] + s[2][1]) + (s[2][2] + s[2][3]);
            float a3 = (s[3][0] + s[3][1]) + (s[3][2] + s[3][3]);
            lsum += (a0 + a1) + (a2 + a3);
        }

        // P -> LDS (bf16, swizzled 8B writes; row = lane's q-row)
        #pragma unroll
        for (int t = 0; t < 4; ++t) {
            uint2 uu;
            uu.x = cvtpk(s[t][0], s[t][1]);
            uu.y = cvtpk(s[t][2], s[t][3]);
            *(uint2*)(psrow + ((32 * t + 8 * g) ^ swz)) = uu;
        }

        bf16x8 pa[2];
        #pragma unroll
        for (int h = 0; h < 2; ++h)
            pa[h] = *(const bf16x8*)(psrow + ((16 * g + 64 * h) ^ swz));
        const char* vbase = (const char*)Vb[bi];
        __builtin_amdgcn_s_setprio(1);
        #pragma unroll
        for (int t = 0; t < 4; ++t)
            #pragma unroll
            for (int h = 0; h < 2; ++h) {
                bf16x8 av = *(const bf16x8*)(vbase + (16 * t + xr) * 128 + ((64 * h + 16 * g) ^ swz));
                accO[t] = __builtin_amdgcn_mfma_f32_16x16x32_bf16(av, pa[h], accO[t], 0, 0, 0);
            }
        __builtin_amdgcn_s_setprio(0);

        __builtin_amdgcn_s_barrier();            // all waves done with buf bi
        if (tt + 2 < tcnt) stage(bi, it + 2);    // safe overwrite after barrier
    }

    // epilogue: reduce lsum across g-groups, store partials
    lsum += __shfl_xor(lsum, 16, 64);
    lsum += __shfl_xor(lsum, 32, 64);

    const size_t prow = (size_t)(b * 8 + c) * 4096 + qrow;
    #pragma unroll
    for (int t = 0; t < 4; ++t) {
        uint2 uu;
        uu.x = cvtpk(accO[t][0], accO[t][1]);
        uu.y = cvtpk(accO[t][2], accO[t][3]);
        *(uint2*)&POb[(prow + xr) * 64 + 16 * t + 4 * g] = uu;
    }
    if (l < 16) Pl[prow + l] = lsum;
}

// ---------------------------------------------------------------------------
// Kernel 3: merge <=8 chunk partials per row -> out. 8 threads/row.
// ---------------------------------------------------------------------------
__global__ __launch_bounds__(256) void merge_kernel(
    const unsigned short* __restrict__ POb, const float* __restrict__ Pl,
    float* __restrict__ out)
{
    const int gid = blockIdx.x * 256 + threadIdx.x;   // 0..131071
    const int r = gid >> 3;
    const int c0 = (gid & 7) * 8;
    const int b = r >> 12, lr = r & 4095;
    const int nc = (lr >> 9) + 1;

    float L = 0.f;
    #pragma unroll
    for (int ci = 0; ci < 8; ++ci)
        if (ci < nc) L += Pl[(size_t)(b * 8 + ci) * 4096 + lr];
    const float rL = 1.0f / L;

    float acc[8];
    #pragma unroll
    for (int j = 0; j < 8; ++j) acc[j] = 0.f;

    #pragma unroll
    for (int ci = 0; ci < 8; ++ci) {
        if (ci < nc) {
            const unsigned short* p = POb + ((size_t)(b * 8 + ci) * 4096 + lr) * 64 + c0;
            uint4 u = *(const uint4*)p;
            const unsigned int us[4] = {u.x, u.y, u.z, u.w};
            #pragma unroll
            for (int k = 0; k < 4; ++k) {
                acc[2 * k]     += __builtin_bit_cast(float, us[k] << 16);
                acc[2 * k + 1] += __builtin_bit_cast(float, us[k] & 0xFFFF0000u);
            }
        }
    }
    float* op = out + (size_t)r * 64 + c0;
    float4 v0, v1;
    v0.x = acc[0] * rL; v0.y = acc[1] * rL; v0.z = acc[2] * rL; v0.w = acc[3] * rL;
    v1.x = acc[4] * rL; v1.y = acc[5] * rL; v1.z = acc[6] * rL; v1.w = acc[7] * rL;
    *(float4*)op = v0;
    *(float4*)(op + 4) = v1;
}

extern "C" void kernel_launch(void* const* d_in, const int* in_sizes, int n_in,
                              void* d_out, int out_size, void* d_ws, size_t ws_size,
                              hipStream_t stream) {
    const float* x  = (const float*)d_in[0];
    const float* Wk = (const float*)d_in[1];
    const float* Wq = (const float*)d_in[2];
    const float* Wv = (const float*)d_in[3];
    float* out = (float*)d_out;

    char* wsb = (char*)d_ws;
    unsigned short* POb = (unsigned short*)wsb;            // [32][4096][64] bf16 = 16MB
    float* Pl = (float*)(wsb + (size_t)17 * 1024 * 1024);  // [32][4096]
    unsigned short* Wt = (unsigned short*)(wsb + (size_t)24 * 1024 * 1024);
    unsigned short* qw = Wt + (size_t)3 * 64 * 1024;       // [16384][64]
    unsigned short* kw = qw + (size_t)16384 * 64;          // [16384][64]
    unsigned short* vT = kw + (size_t)16384 * 64;          // [4][64][4096]

    hipLaunchKernelGGL(wt_kernel, dim3(48), dim3(256), 0, stream, Wk, Wq, Wv, Wt);
    hipLaunchKernelGGL(proj_kernel, dim3(512), dim3(256), 0, stream, x, Wt, qw, kw, vT);
    hipLaunchKernelGGL(attn_kernel, dim3(2048), dim3(256), 0, stream, qw, kw, vT, POb, Pl);
    hipLaunchKernelGGL(merge_kernel, dim3(512), dim3(256), 0, stream, POb, Pl, out);
}